// Round 9
// baseline (975.622 us; speedup 1.0000x reference)
//
#include <hip/hip_runtime.h>
#include <math.h>

// Problem dims (fixed by reference)
#define BB 32
#define DD 256
#define TT 1024
#define KK 1024
#define NN (BB*TT)          // 32768 rows

#define NSTEP 32            // 2 chunks x 16 steps (16 d each)

// ws layout (floats): wsq[1024] @0 ; counts[1024] @1024 ; sse @2048 ;
// rowbest (u64[32768]) @ float-offset 2052 (byte 8208, 8-aligned)

typedef unsigned long long u64;

// wsq[k] = sum_d W[k,d]^2 (fp64, round once). Zero counts/sse, init rowbest.
__global__ void prep_kernel(const float* __restrict__ W, float* __restrict__ wsq,
                            int* __restrict__ counts, float* __restrict__ sse,
                            u64* __restrict__ rowbest) {
    const int k = blockIdx.x;          // 1024 blocks, 64 threads
    const int lane = threadIdx.x;
    const float4 v = ((const float4*)(W + (size_t)k * DD))[lane];
    double s = (double)v.x * v.x + (double)v.y * v.y + (double)v.z * v.z + (double)v.w * v.w;
    #pragma unroll
    for (int m = 32; m > 0; m >>= 1) s += __shfl_down(s, m);
    if (lane == 0) wsq[k] = (float)s;
    if (blockIdx.x < 16) counts[blockIdx.x * 64 + lane] = 0;
    if (blockIdx.x == 0 && lane == 0) *sse = 0.0f;
    const int gid = blockIdx.x * 64 + lane;
    if (gid < NN) rowbest[gid] = ~0ull;
}

// async global->LDS, 16B/lane; LDS dest = wave-uniform base + lane*16 (linear).
__device__ __forceinline__ void gl_lds16(const float* g, void* l) {
    __builtin_amdgcn_global_load_lds((const __attribute__((address_space(1))) void*)g,
                                     (__attribute__((address_space(3))) void*)l, 16, 0, 0);
}

// Argmin-GEMM. Grid 1024 = 512 row-tiles x 2 code-halves (512 codes).
// 256 thr: tx=tid&7 (8 rows each: rows tx*8..+7), ty=tid>>3 (8 codes: ty*8+j).
// z dbuf zst[2][32 d][64 rows] staged by gl_lds (z is t-major: 16B = 4 rows);
// W dbuf wst[2][256 c][4 slots] gl_lds, slot s of code c holds d-group s^((c>>3)&3).
// All LDS reads broadcast/conflict-free; no ds_writes; per-step vmcnt(0)+barrier
// drains only loads issued >=1 step earlier (~free).
// dist mirrors np: s1 = fl(rowsq+wsq); v = fmaf(-2, dot, s1). Per-(row,code) dot:
// single sequential fmaf chain d=0..255 (step asc, q asc, d' asc) — bitwise-matches
// BLAS k-order; validated absmax==0.0 in R1-R8. DO NOT reorder.
// Result per row packed (score_bits<<32)|idx -> global atomicMin (scores>0 so fp32
// bits are order-monotonic; ties -> lower idx = np first-min).
__global__ __launch_bounds__(256, 3) void vq_argmin_kernel(
    const float* __restrict__ z, const float* __restrict__ W,
    const float* __restrict__ wsq, u64* __restrict__ rowbest)
{
    __shared__ float  zst[2][32 * 64];    // 16 KB  [buf][d][row]
    __shared__ float4 wst[2][256 * 4];    // 32 KB  [buf][code*4 + slot]
    const int tid = threadIdx.x;
    const int tx = tid & 7, ty = tid >> 3;
    const int w = tid >> 6, lane = tid & 63;
    const int rb = blockIdx.x >> 1, cb = blockIdx.x & 1;
    const int row0 = rb * 64, C0 = cb * 512;
    const int b = row0 >> 10, t0 = row0 & 1023;
    const float* zbase = z + (size_t)b * DD * TT + t0;

    // ---- rowsq: fp64 64-d chains per quarter, tree (p0+p1)+(p2+p3) (validated)
    float rsq[8];
    {
        double* pscr = (double*)&wst[0][0];      // [4][64]
        float*  fscr = (float*)&zst[1][0];       // [64]
        const int rr = tid & 63, g = tid >> 6;
        const float* zp = zbase + (size_t)g * 64 * TT + rr;
        double s = 0.0;
        #pragma unroll 4
        for (int d = 0; d < 64; ++d) { float v = zp[(size_t)d * TT]; s += (double)v * v; }
        pscr[g * 64 + rr] = s;
        __syncthreads();
        if (tid < 64)
            fscr[tid] = (float)((pscr[tid] + pscr[64 + tid]) + (pscr[128 + tid] + pscr[192 + tid]));
        __syncthreads();
        #pragma unroll
        for (int i = 0; i < 8; ++i) rsq[i] = fscr[tx * 8 + i];
        __syncthreads();   // scratch free before staging overwrites
    }

    // ---- prologue staging: W[0] -> wst[0], z slab0 -> zst[0]
    {
        const float* wc = W + (size_t)C0 * DD;
        #pragma unroll
        for (int k = 0; k < 4; ++k) {
            const int idx = k * 256 + tid, c = idx >> 2, s = idx & 3;
            gl_lds16(wc + (size_t)c * DD + 4 * (s ^ ((c >> 3) & 3)),
                     (char*)&wst[0][0] + (size_t)idx * 16);
        }
        #pragma unroll
        for (int k = 0; k < 2; ++k) {
            const int idx = k * 256 + tid, d = idx >> 4, r4 = (idx & 15) * 4;
            gl_lds16(zbase + (size_t)d * TT + r4, (char*)&zst[0][0] + (size_t)idx * 16);
        }
    }

    float minv[8]; int mini[8];
    #pragma unroll
    for (int i = 0; i < 8; ++i) { minv[i] = 3.4e38f; mini[i] = 0; }
    float acc[8][8];
    float wq[8];

    for (int t = 0; t < NSTEP; ++t) {
        const int sl = t & 15, ch = t >> 4, h = t & 1;
        asm volatile("s_waitcnt vmcnt(0)" ::: "memory");   // all outstanding issued >=1 step ago
        __syncthreads();
        // issue W[t+1] into wst[(t+1)&1] (its readers finished at step t-1)
        if (t + 1 < NSTEP) {
            const int tn = t + 1;
            const float* wc = W + (size_t)(C0 + (tn >> 4) * 256) * DD + (tn & 15) * 16;
            #pragma unroll
            for (int k = 0; k < 4; ++k) {
                const int idx = k * 256 + tid, c = idx >> 2, s = idx & 3;
                gl_lds16(wc + (size_t)c * DD + 4 * (s ^ ((c >> 3) & 3)),
                         (char*)&wst[tn & 1][0] + (size_t)idx * 16);
            }
        }
        // even t: issue z slab for steps t+2,t+3 into zst[((t+2)>>1)&1]
        if ((t & 1) == 0 && t + 2 < NSTEP) {
            const int dn = ((t + 2) & 15) * 16;
            char* dst = (char*)&zst[((t + 2) >> 1) & 1][0];
            #pragma unroll
            for (int k = 0; k < 2; ++k) {
                const int idx = k * 256 + tid, d = idx >> 4, r4 = (idx & 15) * 4;
                gl_lds16(zbase + (size_t)(dn + d) * TT + r4, dst + (size_t)idx * 16);
            }
        }
        if (sl == 0) {
            #pragma unroll
            for (int i = 0; i < 8; ++i)
                #pragma unroll
                for (int j = 0; j < 8; ++j) acc[i][j] = 0.0f;
            #pragma unroll
            for (int j = 0; j < 8; ++j) wq[j] = wsq[C0 + ch * 256 + ty * 8 + j];
        }
        // compute: 4 q-groups x 4 d' x 8 rows x 8 codes
        const float*  zb = &zst[(t >> 1) & 1][h * 16 * 64];
        const float4* wb = &wst[h][ty * 32];
        __builtin_amdgcn_s_setprio(1);
        for (int q = 0; q < 4; ++q) {
            float4 wf[8];
            const float4* wp = wb + (q ^ (ty & 3));
            #pragma unroll
            for (int j = 0; j < 8; ++j) wf[j] = wp[j * 4];
            #pragma unroll
            for (int dp = 0; dp < 4; ++dp) {
                const float4* zp = (const float4*)(zb + (q * 4 + dp) * 64 + tx * 8);
                const float4 za = zp[0], zc = zp[1];
                #pragma unroll
                for (int j = 0; j < 8; ++j) {
                    const float wv = dp == 0 ? wf[j].x : dp == 1 ? wf[j].y
                                   : dp == 2 ? wf[j].z : wf[j].w;
                    acc[0][j] = fmaf(za.x, wv, acc[0][j]);
                    acc[1][j] = fmaf(za.y, wv, acc[1][j]);
                    acc[2][j] = fmaf(za.z, wv, acc[2][j]);
                    acc[3][j] = fmaf(za.w, wv, acc[3][j]);
                    acc[4][j] = fmaf(zc.x, wv, acc[4][j]);
                    acc[5][j] = fmaf(zc.y, wv, acc[5][j]);
                    acc[6][j] = fmaf(zc.z, wv, acc[6][j]);
                    acc[7][j] = fmaf(zc.w, wv, acc[7][j]);
                }
            }
        }
        __builtin_amdgcn_s_setprio(0);
        if (sl == 15) {
            // score + running argmin (thread scans ch asc, j asc; strict <)
            #pragma unroll
            for (int j = 0; j < 8; ++j) {
                const int c = C0 + ch * 256 + ty * 8 + j;
                #pragma unroll
                for (int i = 0; i < 8; ++i) {
                    float s1 = rsq[i] + wq[j];               // rounding 1 (np A+B)
                    float v = fmaf(-2.0f, acc[i][j], s1);    // rounding 2 (np (A+B)-2P)
                    if (v < minv[i]) { minv[i] = v; mini[i] = c; }
                }
            }
        }
    }

    // ---- reduce: shuffle over ty-in-wave (masks 8,16,32), LDS over waves, atomicMin
    __syncthreads();                        // zst free
    float* cvs = (float*)&zst[0][0];        // [4][64]
    int*   cis = (int*)&zst[0][0] + 256;    // [4][64]
    #pragma unroll
    for (int i = 0; i < 8; ++i) {
        float v = minv[i]; int ix = mini[i];
        #pragma unroll
        for (int m = 8; m < 64; m <<= 1) {
            float ov = __shfl_xor(v, m);
            int   oi = __shfl_xor(ix, m);
            if (ov < v || (ov == v && oi < ix)) { v = ov; ix = oi; }
        }
        if (lane < 8) { cvs[w * 64 + lane * 8 + i] = v; cis[w * 64 + lane * 8 + i] = ix; }
    }
    __syncthreads();
    if (tid < 64) {
        float bv = cvs[tid]; int bi = cis[tid];
        #pragma unroll
        for (int ww = 1; ww < 4; ++ww) {
            float v = cvs[ww * 64 + tid]; int ii = cis[ww * 64 + tid];
            if (v < bv || (v == bv && ii < bi)) { bv = v; bi = ii; }
        }
        const u64 key = ((u64)__float_as_uint(bv) << 32) | (unsigned)bi;
        atomicMin(&rowbest[row0 + tid], key);
    }
}

// Output kernel: combine halves (already in rowbest), gather, straight-through,
// SSE, counts. 512 blocks x 256 thr, 64 rows each.
__global__ void vq_out_kernel(const float* __restrict__ z, const float* __restrict__ W,
                              const u64* __restrict__ rowbest, float* __restrict__ out,
                              int* __restrict__ counts, float* __restrict__ sse) {
    __shared__ int idxs[64];
    __shared__ float ssescr[4];
    const int tid = threadIdx.x;
    const int w = tid >> 6;
    const int row0 = blockIdx.x * 64;
    const int b = row0 >> 10, t0 = row0 & 1023;
    const size_t bbase = (size_t)b * DD * TT;
    if (tid < 64) {
        const int ix = (int)(rowbest[row0 + tid] & 0xffffffffull);
        idxs[tid] = ix;
        atomicAdd(&counts[ix], 1);
    }
    __syncthreads();
    const int tg = tid & 15;       // 16 t-groups of 4 rows
    const int dg = tid >> 4;       // 16 d-groups of 16
    const int t4 = tg * 4;
    int ixs[4];
    #pragma unroll
    for (int m = 0; m < 4; ++m) ixs[m] = idxs[t4 + m];
    float ssel = 0.0f;
    #pragma unroll
    for (int k4 = 0; k4 < 4; ++k4) {
        const int d0 = dg * 16 + k4 * 4;
        float wr[4][4];
        #pragma unroll
        for (int m = 0; m < 4; ++m) {
            float4 wv = *(const float4*)(W + (size_t)ixs[m] * DD + d0);
            wr[m][0] = wv.x; wr[m][1] = wv.y; wr[m][2] = wv.z; wr[m][3] = wv.w;
        }
        #pragma unroll
        for (int dd = 0; dd < 4; ++dd) {
            const int d = d0 + dd;
            const size_t base = bbase + (size_t)d * TT + t0 + t4;
            float4 zv = *(const float4*)(z + base);
            float e0 = wr[0][dd] - zv.x, e1 = wr[1][dd] - zv.y;
            float e2 = wr[2][dd] - zv.z, e3 = wr[3][dd] - zv.w;
            float4 o;
            o.x = zv.x + e0; o.y = zv.y + e1; o.z = zv.z + e2; o.w = zv.w + e3;
            *(float4*)(out + base) = o;
            ssel += (e0 * e0 + e1 * e1) + (e2 * e2 + e3 * e3);
        }
    }
    #pragma unroll
    for (int m = 32; m > 0; m >>= 1) ssel += __shfl_down(ssel, m);
    if ((tid & 63) == 0) ssescr[w] = ssel;
    __syncthreads();
    if (tid == 0) atomicAdd(sse, (ssescr[0] + ssescr[1]) + (ssescr[2] + ssescr[3]));
}

// reg_loss = 1.25 * sse / numel ; perplexity = exp(-sum p*log(p+1e-10))
__global__ void finalize_kernel(const int* __restrict__ counts, const float* __restrict__ sse,
                                float* __restrict__ out) {
    float s = 0.0f;
    for (int k = threadIdx.x; k < KK; k += 256) {
        float p = (float)counts[k] / (float)NN;
        s += p * logf(p + 1e-10f);
    }
    #pragma unroll
    for (int m = 32; m > 0; m >>= 1) s += __shfl_down(s, m);
    __shared__ float wsum[4];
    if ((threadIdx.x & 63) == 0) wsum[threadIdx.x >> 6] = s;
    __syncthreads();
    if (threadIdx.x == 0) {
        float ent = (wsum[0] + wsum[1]) + (wsum[2] + wsum[3]);
        out[(size_t)BB * DD * TT]     = 1.25f * (*sse) / (float)(BB * DD * TT);
        out[(size_t)BB * DD * TT + 1] = expf(-ent);
    }
}

extern "C" void kernel_launch(void* const* d_in, const int* in_sizes, int n_in,
                              void* d_out, int out_size, void* d_ws, size_t ws_size,
                              hipStream_t stream) {
    const float* z = (const float*)d_in[0];   // (32, 256, 1024) fp32
    const float* W = (const float*)d_in[1];   // (1024, 256) fp32
    float* out = (float*)d_out;               // 8388608 + 2 fp32

    float* wsq    = (float*)d_ws;
    int*   counts = (int*)(wsq + 1024);
    float* sse    = (float*)(counts + 1024);
    u64*   rowbest = (u64*)((float*)d_ws + 2052);   // byte 8208, 8-aligned

    prep_kernel<<<1024, 64, 0, stream>>>(W, wsq, counts, sse, rowbest);
    vq_argmin_kernel<<<1024, 256, 0, stream>>>(z, W, wsq, rowbest);
    vq_out_kernel<<<512, 256, 0, stream>>>(z, W, rowbest, out, counts, sse);
    finalize_kernel<<<1, 256, 0, stream>>>(counts, sse, out);
}

// Round 10
// 269.931 us; speedup vs baseline: 3.6143x; 3.6143x over previous
//
#include <hip/hip_runtime.h>
#include <math.h>

// Problem dims (fixed by reference)
#define BB 32
#define DD 256
#define TT 1024
#define KK 1024
#define NN (BB*TT)          // 32768 rows

// argmin-GEMM tiling
#define BROWS 64            // rows per block
#define CCH   256           // codes per chunk
#define DSL   64            // d per slice
#define NSTEP 16            // 4 chunks x 4 slices

// ---------------------------------------------------------------------------
// ws layout (elements): float wsq[1024] @0 ; int counts[1024] @1024 ; float sse @2048
// ---------------------------------------------------------------------------

// wsq[k] = sum_d W[k,d]^2 (fp64 accumulate, round once). Zeroes counts+sse.
__global__ void prep_kernel(const float* __restrict__ W, float* __restrict__ wsq,
                            int* __restrict__ counts, float* __restrict__ sse) {
    const int k = blockIdx.x;          // 1024 blocks, 64 threads
    const int lane = threadIdx.x;
    const float4 v = ((const float4*)(W + (size_t)k * DD))[lane];
    double s = (double)v.x * v.x + (double)v.y * v.y + (double)v.z * v.z + (double)v.w * v.w;
    #pragma unroll
    for (int m = 32; m > 0; m >>= 1) s += __shfl_down(s, m);
    if (lane == 0) wsq[k] = (float)s;
    if (blockIdx.x < 16) counts[blockIdx.x * 64 + lane] = 0;
    if (blockIdx.x == 0 && lane == 0) *sse = 0.0f;
}

// W LDS slots: value at (r, slot) is W[..r..][4*(slot ^ sw(r))..]; read at slot = q ^ sw(r).
__device__ __forceinline__ int swz_w(int r, int q) { return r * 16 + (q ^ ((r >> 3) & 7)); }
// z slots: extra ^(r&7) term -> staging writes (lanes sweep r) are 2-way/phase (free);
// reads are ty-broadcast so their bank pattern is irrelevant.
__device__ __forceinline__ int swz_z(int r, int q) { return r * 16 + (q ^ (r & 7) ^ ((r >> 3) & 7)); }

// async global->LDS, 16B per lane; LDS dest = wave-uniform base + lane*16 (linear).
__device__ __forceinline__ void gl_lds16(const float* g, void* l) {
    __builtin_amdgcn_global_load_lds((const __attribute__((address_space(1))) void*)g,
                                     (__attribute__((address_space(3))) void*)l, 16, 0, 0);
}

// Fused: rowsq + argmin-GEMM + gather/straight-through/SSE/counts.
// Block: 64 rows x all 1024 codes (4 chunks of 256). 256 thr = 8(ty) x 32(tx), 8x8 tile.
// dist mirrors np:  s1 = fl(rowsq + wsq);  v = fmaf(-2, dot, s1).
// Per-(row,code) dot: single sequential fmaf chain over d=0..255 in order
// (bitwise-matches BLAS k-order; validated absmax==0.0 in R1-R9). DO NOT reorder.
// DO NOT add #pragma unroll to the q-loop (R4 spill lesson).
__global__ __launch_bounds__(256, 2) void vq_fused_kernel(
    const float* __restrict__ z, const float* __restrict__ W,
    const float* __restrict__ wsq, float* __restrict__ out,
    int* __restrict__ counts, float* __restrict__ sse)
{
    __shared__ float4 zs[BROWS * 16];   // 16 KB (reused as idx/sse scratch at the end)
    __shared__ float4 ws[CCH * 16];     // 64 KB
    const int tid = threadIdx.x;
    const int tx = tid & 31, ty = tid >> 5;
    const int w = tid >> 6, lane = tid & 63;
    const int row0 = blockIdx.x * BROWS;
    const int b = row0 >> 10, t0 = row0 & 1023;
    const size_t bbase = (size_t)b * DD * TT;
    const float* zbase = z + bbase + t0;

    // ---- phase 0: per-wave rowsq (fp64, bitwise == ((g0+g1)+(g2+g3)) of 64-elem chains)
    float rsq[8];
    {
        const int ro = lane & 15;          // row offset within wave's 16 rows
        const int g  = lane >> 4;          // d-quarter 0..3
        const float* zp = zbase + (size_t)g * 64 * TT + (16 * w + ro);
        double s = 0.0;
        #pragma unroll 4
        for (int d = 0; d < 64; ++d) { float v = zp[(size_t)d * TT]; s += (double)v * v; }
        s += __shfl_xor(s, 16);            // g0+g1 / g2+g3 (fp64 add commutative: bitwise safe)
        s += __shfl_xor(s, 32);            // (g0+g1)+(g2+g3)
        float f = (float)s;
        #pragma unroll
        for (int i = 0; i < 8; ++i) rsq[i] = __shfl(f, (ty & 1) * 8 + i);
    }

    float minv[8]; int mini[8];
    #pragma unroll
    for (int i = 0; i < 8; ++i) { minv[i] = 3.4e38f; mini[i] = 0; }

    // z-prefetch registers (next step's slab); staging identity: thread covers
    // row zr = tid&63, q-group 4w..4w+3
    const int zr = tid & 63;
    const int zq0 = w * 4;
    float4 zreg[4];
    {   // prologue: load slab for step 0 (sl=0)
        #pragma unroll
        for (int j = 0; j < 4; ++j) {
            const float* zp = zbase + (size_t)((zq0 + j) * 4) * TT + zr;
            zreg[j].x = zp[0]; zreg[j].y = zp[(size_t)TT];
            zreg[j].z = zp[(size_t)2 * TT]; zreg[j].w = zp[(size_t)3 * TT];
        }
    }

    const int wr0 = w * 64 + (lane >> 4); // W-stage row for k=0
    const int wslot = lane & 15;
    char* const wlbase = (char*)ws + (size_t)w * 16384;

    float acc[8][8];
    float wq[8];

    for (int s = 0; s < NSTEP; ++s) {
        const int sl = s & 3, ch = s >> 2;
        __syncthreads();   // waves done reading zs/ws of previous step; z-prefetch drained
        // write z slab from regs (4x ds_write_b128, 2-way/phase swizzle)
        #pragma unroll
        for (int j = 0; j < 4; ++j) zs[swz_z(zr, zq0 + j)] = zreg[j];
        // stage W chunk-slice direct to LDS: linear dest, pre-swizzled source
        {
            const float* wch = W + (size_t)(ch * CCH) * DD + sl * DSL;
            #pragma unroll
            for (int k = 0; k < 16; ++k) {
                int r = wr0 + k * 4;
                const float* g = wch + (size_t)r * DD + 4 * (wslot ^ ((r >> 3) & 7));
                gl_lds16(g, wlbase + k * 1024);
            }
        }
        __syncthreads();   // drains lgkm (zs) + vmcnt (W loads) [compiler-inserted]

        if (sl == 0) {
            #pragma unroll
            for (int i = 0; i < 8; ++i)
                #pragma unroll
                for (int j = 0; j < 8; ++j) acc[i][j] = 0.0f;
            #pragma unroll
            for (int j = 0; j < 8; ++j) wq[j] = wsq[ch * CCH + tx * 8 + j];
        }
        // prefetch next step's z slab into regs (hides under compute)
        if (s < NSTEP - 1) {
            const int sln = (s + 1) & 3;
            #pragma unroll
            for (int j = 0; j < 4; ++j) {
                const float* zp = zbase + (size_t)(sln * DSL + (zq0 + j) * 4) * TT + zr;
                zreg[j].x = zp[0]; zreg[j].y = zp[(size_t)TT];
                zreg[j].z = zp[(size_t)2 * TT]; zreg[j].w = zp[(size_t)3 * TT];
            }
        }
        // 8x8x(64d) register-tile FMA; d-order: q ascending, then x,y,z,w
        __builtin_amdgcn_s_setprio(1);
        for (int q = 0; q < 16; ++q) {      // no unroll pragma (R4 spill lesson)
            float4 zf[8], wf[8];
            #pragma unroll
            for (int i = 0; i < 8; ++i) zf[i] = zs[swz_z(ty * 8 + i, q)];
            #pragma unroll
            for (int j = 0; j < 8; ++j) wf[j] = ws[swz_w(tx * 8 + j, q)];
            #pragma unroll
            for (int i = 0; i < 8; ++i)
                #pragma unroll
                for (int j = 0; j < 8; ++j) {
                    acc[i][j] = fmaf(zf[i].x, wf[j].x, acc[i][j]);
                    acc[i][j] = fmaf(zf[i].y, wf[j].y, acc[i][j]);
                    acc[i][j] = fmaf(zf[i].z, wf[j].z, acc[i][j]);
                    acc[i][j] = fmaf(zf[i].w, wf[j].w, acc[i][j]);
                }
        }
        __builtin_amdgcn_s_setprio(0);
        if (sl == 3) {
            // score + running argmin (codes ascending -> first-min like np.argmin)
            #pragma unroll
            for (int j = 0; j < 8; ++j) {
                int c = ch * CCH + tx * 8 + j;
                #pragma unroll
                for (int i = 0; i < 8; ++i) {
                    float s1 = rsq[i] + wq[j];               // rounding 1 (np A+B)
                    float v = fmaf(-2.0f, acc[i][j], s1);    // rounding 2 (np (A+B)-2P)
                    if (v < minv[i]) { minv[i] = v; mini[i] = c; }
                }
            }
        }
    }

    __syncthreads();                 // all compute done; zs becomes scratch
    int* idxs = (int*)&zs[0];        // 64 ints
    float* ssescr = (float*)&zs[0] + 64;
    // reduce across the 32 tx lanes of each row; ties -> lowest index
    #pragma unroll
    for (int i = 0; i < 8; ++i) {
        float v = minv[i]; int ix = mini[i];
        #pragma unroll
        for (int m = 1; m < 32; m <<= 1) {
            float ov = __shfl_xor(v, m);
            int   oi = __shfl_xor(ix, m);
            if (ov < v || (ov == v && oi < ix)) { v = ov; ix = oi; }
        }
        if (tx == 0) {
            idxs[ty * 8 + i] = ix;
            atomicAdd(&counts[ix], 1);
        }
    }
    __syncthreads();

    // ---- fused gather / straight-through / SSE over this block's 64 rows x 256 d
    const int tg = tid & 15;       // t-quarter (4 rows)
    const int dg = tid >> 4;       // 16 d-groups of 16
    const int t4 = tg * 4;
    int ixs[4];
    #pragma unroll
    for (int m = 0; m < 4; ++m) ixs[m] = idxs[t4 + m];
    float ssel = 0.0f;
    #pragma unroll
    for (int k4 = 0; k4 < 4; ++k4) {
        const int d0 = dg * 16 + k4 * 4;
        float wr[4][4];
        #pragma unroll
        for (int m = 0; m < 4; ++m) {
            float4 wv = *(const float4*)(W + (size_t)ixs[m] * DD + d0);
            wr[m][0] = wv.x; wr[m][1] = wv.y; wr[m][2] = wv.z; wr[m][3] = wv.w;
        }
        #pragma unroll
        for (int dd = 0; dd < 4; ++dd) {
            const int d = d0 + dd;
            const size_t base = bbase + (size_t)d * TT + t0 + t4;
            float4 zv = *(const float4*)(z + base);
            float e0 = wr[0][dd] - zv.x, e1 = wr[1][dd] - zv.y;
            float e2 = wr[2][dd] - zv.z, e3 = wr[3][dd] - zv.w;
            float4 o;
            o.x = zv.x + e0; o.y = zv.y + e1; o.z = zv.z + e2; o.w = zv.w + e3;
            *(float4*)(out + base) = o;
            ssel += (e0 * e0 + e1 * e1) + (e2 * e2 + e3 * e3);
        }
    }
    #pragma unroll
    for (int m = 32; m > 0; m >>= 1) ssel += __shfl_down(ssel, m);
    if (lane == 0) ssescr[w] = ssel;
    __syncthreads();
    if (tid == 0) atomicAdd(sse, (ssescr[0] + ssescr[1]) + (ssescr[2] + ssescr[3]));
}

// reg_loss = 1.25 * sse / numel ; perplexity = exp(-sum p*log(p+1e-10))
__global__ void finalize_kernel(const int* __restrict__ counts, const float* __restrict__ sse,
                                float* __restrict__ out) {
    float s = 0.0f;
    for (int k = threadIdx.x; k < KK; k += 256) {
        float p = (float)counts[k] / (float)NN;
        s += p * logf(p + 1e-10f);
    }
    #pragma unroll
    for (int m = 32; m > 0; m >>= 1) s += __shfl_down(s, m);
    __shared__ float wsum[4];
    if ((threadIdx.x & 63) == 0) wsum[threadIdx.x >> 6] = s;
    __syncthreads();
    if (threadIdx.x == 0) {
        float ent = (wsum[0] + wsum[1]) + (wsum[2] + wsum[3]);
        out[(size_t)BB * DD * TT]     = 1.25f * (*sse) / (float)(BB * DD * TT);
        out[(size_t)BB * DD * TT + 1] = expf(-ent);
    }
}

extern "C" void kernel_launch(void* const* d_in, const int* in_sizes, int n_in,
                              void* d_out, int out_size, void* d_ws, size_t ws_size,
                              hipStream_t stream) {
    const float* z = (const float*)d_in[0];   // (32, 256, 1024) fp32
    const float* W = (const float*)d_in[1];   // (1024, 256) fp32
    float* out = (float*)d_out;               // 8388608 + 2 fp32

    float* wsq    = (float*)d_ws;
    int*   counts = (int*)(wsq + 1024);
    float* sse    = (float*)(counts + 1024);

    prep_kernel<<<1024, 64, 0, stream>>>(W, wsq, counts, sse);
    vq_fused_kernel<<<NN / BROWS, 256, 0, stream>>>(z, W, wsq, out, counts, sse);
    finalize_kernel<<<1, 256, 0, stream>>>(counts, sse, out);
}

// Round 11
// 258.069 us; speedup vs baseline: 3.7805x; 1.0460x over previous
//
#include <hip/hip_runtime.h>
#include <math.h>

// Problem dims (fixed by reference)
#define BB 32
#define DD 256
#define TT 1024
#define KK 1024
#define NN (BB*TT)          // 32768 rows

#define BROWS 128           // rows per block (one block per CU)
#define NSTEP 32            // 2 code-chunks x 16 slices of 16 d

// ws layout (elements): float wsq[1024] @0 ; int counts[1024] @1024 ; float sse @2048

// wsq[k] = sum_d W[k,d]^2 (fp64 accumulate, round once). Zeroes counts+sse.
__global__ void prep_kernel(const float* __restrict__ W, float* __restrict__ wsq,
                            int* __restrict__ counts, float* __restrict__ sse) {
    const int k = blockIdx.x;          // 1024 blocks, 64 threads
    const int lane = threadIdx.x;
    const float4 v = ((const float4*)(W + (size_t)k * DD))[lane];
    double s = (double)v.x * v.x + (double)v.y * v.y + (double)v.z * v.z + (double)v.w * v.w;
    #pragma unroll
    for (int m = 32; m > 0; m >>= 1) s += __shfl_down(s, m);
    if (lane == 0) wsq[k] = (float)s;
    if (blockIdx.x < 16) counts[blockIdx.x * 64 + lane] = 0;
    if (blockIdx.x == 0 && lane == 0) *sse = 0.0f;
}

// async global->LDS, 16B/lane; LDS dest = wave-uniform base + lane*16 (linear).
__device__ __forceinline__ void gl_lds16(const float* g, void* l) {
    __builtin_amdgcn_global_load_lds((const __attribute__((address_space(1))) void*)g,
                                     (__attribute__((address_space(3))) void*)l, 16, 0, 0);
}

// Fused VQ. 512 thr = 8 waves, 1 block/CU (grid 256), 2 waves/SIMD.
// Tile: wave wid owns rows wid*16..+15; lane owns codes lane*8..+7 of the
// current 512-code chunk -> per-thread 16x8 acc (21.3 fmaf per LDS read vs 16
// at 8x8 — the R10 co-saturation fix).
//  - zst[2][16 d][128 r] (2x8 KB, gl_lds direct; z is t-major so 16B = 4 rows):
//    ALL zf reads are wave-uniform broadcasts (ty uniform per wave).
//  - wst[2][512 c][4 slots] (2x32 KB, gl_lds linear dest + 4-slot XOR source;
//    read slot = q ^ (lane&3); ~4-way aliasing = 1.58x, negligible at new ratio).
// dist mirrors np: s1 = fl(rowsq+wsq); v = fmaf(-2, dot, s1). Per-(row,code)
// dot: single sequential fmaf chain d=0..255 (t asc -> q asc -> dp asc, one
// fmaf per d) — bitwise same chain as R1-R10 (validated absmax==0.0 8x).
// DO NOT reorder. acc static-indexed only (rule #20); q-loop rolled (R4).
__global__ __launch_bounds__(512, 2) void vq_fused_kernel(
    const float* __restrict__ z, const float* __restrict__ W,
    const float* __restrict__ wsq, float* __restrict__ out,
    int* __restrict__ counts, float* __restrict__ sse)
{
    __shared__ float zst[2][16 * 128];   // 16 KB (zst[0] reused as idx scratch at end)
    __shared__ float wst[2][16 * 512];   // 64 KB (wst[0] reused as sse scratch at end)
    __shared__ float rsql[128];
    const int tid = threadIdx.x;
    const int wid = tid >> 6, lane = tid & 63;
    const int row0 = blockIdx.x * BROWS;
    const int b = row0 >> 10, t0 = row0 & 1023;
    const size_t bbase = (size_t)b * DD * TT;
    const float* zbase = z + bbase + t0;

    // ---- prologue staging for step 0 (latency hides under rowsq)
    {
        char* dw = (char*)&wst[0][0];
        #pragma unroll
        for (int k = 0; k < 4; ++k) {
            const int m = k * 512 + tid, c = m >> 2, s = m & 3;
            gl_lds16(W + (size_t)c * DD + 4 * (s ^ ((c >> 3) & 3)), dw + (size_t)m * 16);
        }
        const int d = tid >> 5, r4 = (tid & 31) * 4;
        gl_lds16(zbase + (size_t)d * TT + r4, (char*)&zst[0][0] + (size_t)tid * 16);
    }

    // ---- rowsq: per row 4 fp64 64-d chains, tree (p0+p1)+(p2+p3) (validated form)
    {
        double* pscr = (double*)&zst[1][0];        // 4 KB scratch (zst[1] free pre-loop)
        const int rr = tid & 127, g = tid >> 7;
        const float* zp = zbase + (size_t)g * 64 * TT + rr;
        double s = 0.0;
        #pragma unroll 4
        for (int d = 0; d < 64; ++d) { float v = zp[(size_t)d * TT]; s += (double)v * v; }
        pscr[g * 128 + rr] = s;
        __syncthreads();
        if (tid < 128)
            rsql[tid] = (float)((pscr[tid] + pscr[128 + tid]) + (pscr[256 + tid] + pscr[384 + tid]));
    }

    float minv[16]; int mini[16];
    #pragma unroll
    for (int i = 0; i < 16; ++i) { minv[i] = 3.4e38f; mini[i] = 0; }
    float acc[16][8];
    const int wsw = lane & 3;

    for (int t = 0; t < NSTEP; ++t) {
        const int ch = t >> 4, sl = t & 15, h = t & 1;
        __syncthreads();   // drains vmcnt/lgkm: buffers[h] (staged at t-1) ready;
                           // at t=0 also fences rowsq scratch in zst[1]
        // issue step t+1 staging NOW; lands during ~4096 cyc of compute below
        if (t + 1 < NSTEP) {
            const int tn = t + 1, chn = tn >> 4, sln = tn & 15;
            const float* wc = W + (size_t)(chn * 512) * DD + sln * 16;
            char* dw = (char*)&wst[tn & 1][0];
            #pragma unroll
            for (int k = 0; k < 4; ++k) {
                const int m = k * 512 + tid, c = m >> 2, s = m & 3;
                gl_lds16(wc + (size_t)c * DD + 4 * (s ^ ((c >> 3) & 3)), dw + (size_t)m * 16);
            }
            const int d = tid >> 5, r4 = (tid & 31) * 4;
            gl_lds16(zbase + (size_t)(sln * 16 + d) * TT + r4,
                     (char*)&zst[tn & 1][0] + (size_t)tid * 16);
        }
        if (sl == 0) {
            #pragma unroll
            for (int i = 0; i < 16; ++i)
                #pragma unroll
                for (int j = 0; j < 8; ++j) acc[i][j] = 0.0f;
        }
        // compute: 4 q-groups x (8 wf b128 + 4x4 zf broadcast b128 + 512 fmaf)
        const float*  zb  = &zst[h][0];
        const float4* wb4 = (const float4*)&wst[h][0];
        __builtin_amdgcn_s_setprio(1);
        #pragma clang loop unroll(disable)
        for (int q = 0; q < 4; ++q) {
            const float4* wp = wb4 + lane * 32 + (q ^ wsw);
            float4 wf[8];
            #pragma unroll
            for (int j = 0; j < 8; ++j) wf[j] = wp[j * 4];
            #pragma unroll
            for (int dp = 0; dp < 4; ++dp) {
                const float4* zp4 = (const float4*)(zb + (q * 4 + dp) * 128 + wid * 16);
                const float4 za = zp4[0], zc = zp4[1], ze = zp4[2], zg = zp4[3];
                #pragma unroll
                for (int j = 0; j < 8; ++j) {
                    const float wv = dp == 0 ? wf[j].x : dp == 1 ? wf[j].y
                                   : dp == 2 ? wf[j].z : wf[j].w;
                    acc[0][j]  = fmaf(za.x, wv, acc[0][j]);
                    acc[1][j]  = fmaf(za.y, wv, acc[1][j]);
                    acc[2][j]  = fmaf(za.z, wv, acc[2][j]);
                    acc[3][j]  = fmaf(za.w, wv, acc[3][j]);
                    acc[4][j]  = fmaf(zc.x, wv, acc[4][j]);
                    acc[5][j]  = fmaf(zc.y, wv, acc[5][j]);
                    acc[6][j]  = fmaf(zc.z, wv, acc[6][j]);
                    acc[7][j]  = fmaf(zc.w, wv, acc[7][j]);
                    acc[8][j]  = fmaf(ze.x, wv, acc[8][j]);
                    acc[9][j]  = fmaf(ze.y, wv, acc[9][j]);
                    acc[10][j] = fmaf(ze.z, wv, acc[10][j]);
                    acc[11][j] = fmaf(ze.w, wv, acc[11][j]);
                    acc[12][j] = fmaf(zg.x, wv, acc[12][j]);
                    acc[13][j] = fmaf(zg.y, wv, acc[13][j]);
                    acc[14][j] = fmaf(zg.z, wv, acc[14][j]);
                    acc[15][j] = fmaf(zg.w, wv, acc[15][j]);
                }
            }
        }
        __builtin_amdgcn_s_setprio(0);
        if (sl == 15) {
            // score + running argmin (codes asc within thread: ch asc, j asc; strict <)
            float wq[8];
            #pragma unroll
            for (int j = 0; j < 8; ++j) wq[j] = wsq[ch * 512 + lane * 8 + j];
            #pragma unroll
            for (int i = 0; i < 16; ++i) {
                const float rs = rsql[wid * 16 + i];
                #pragma unroll
                for (int j = 0; j < 8; ++j) {
                    const float s1 = rs + wq[j];             // rounding 1 (np A+B)
                    const float v = fmaf(-2.0f, acc[i][j], s1); // rounding 2 (np (A+B)-2P)
                    if (v < minv[i]) { minv[i] = v; mini[i] = ch * 512 + lane * 8 + j; }
                }
            }
        }
    }

    // ---- per-wave argmin reduce over 64 lanes (lane asc = code asc; tie -> lower)
    __syncthreads();                     // compute done; zst/wst become scratch
    int* idxs = (int*)&zst[0][0];        // 128 ints
    float* ssescr = (float*)&wst[0][0];  // 8 floats
    #pragma unroll
    for (int i = 0; i < 16; ++i) {
        float v = minv[i]; int ix = mini[i];
        #pragma unroll
        for (int m = 1; m < 64; m <<= 1) {
            float ov = __shfl_xor(v, m);
            int   oi = __shfl_xor(ix, m);
            if (ov < v || (ov == v && oi < ix)) { v = ov; ix = oi; }
        }
        if (lane == 0) {
            idxs[wid * 16 + i] = ix;
            atomicAdd(&counts[ix], 1);
        }
    }
    __syncthreads();

    // ---- fused gather / straight-through / SSE over 128 rows x 256 d
    const int tg = tid & 31;       // 32 t-groups of 4 rows
    const int dg = tid >> 5;       // 16 d-groups of 16
    const int t4 = tg * 4;
    int ixs[4];
    #pragma unroll
    for (int m = 0; m < 4; ++m) ixs[m] = idxs[t4 + m];
    float ssel = 0.0f;
    #pragma unroll
    for (int k4 = 0; k4 < 4; ++k4) {
        const int d0 = dg * 16 + k4 * 4;
        float wr[4][4];
        #pragma unroll
        for (int m = 0; m < 4; ++m) {
            float4 wv = *(const float4*)(W + (size_t)ixs[m] * DD + d0);
            wr[m][0] = wv.x; wr[m][1] = wv.y; wr[m][2] = wv.z; wr[m][3] = wv.w;
        }
        #pragma unroll
        for (int dd = 0; dd < 4; ++dd) {
            const int d = d0 + dd;
            const size_t base = bbase + (size_t)d * TT + t0 + t4;
            float4 zv = *(const float4*)(z + base);
            float e0 = wr[0][dd] - zv.x, e1 = wr[1][dd] - zv.y;
            float e2 = wr[2][dd] - zv.z, e3 = wr[3][dd] - zv.w;
            float4 o;
            o.x = zv.x + e0; o.y = zv.y + e1; o.z = zv.z + e2; o.w = zv.w + e3;
            *(float4*)(out + base) = o;
            ssel += (e0 * e0 + e1 * e1) + (e2 * e2 + e3 * e3);
        }
    }
    #pragma unroll
    for (int m = 32; m > 0; m >>= 1) ssel += __shfl_down(ssel, m);
    if (lane == 0) ssescr[wid] = ssel;
    __syncthreads();
    if (tid == 0)
        atomicAdd(sse, ((ssescr[0] + ssescr[1]) + (ssescr[2] + ssescr[3]))
                     + ((ssescr[4] + ssescr[5]) + (ssescr[6] + ssescr[7])));
}

// reg_loss = 1.25 * sse / numel ; perplexity = exp(-sum p*log(p+1e-10))
__global__ void finalize_kernel(const int* __restrict__ counts, const float* __restrict__ sse,
                                float* __restrict__ out) {
    float s = 0.0f;
    for (int k = threadIdx.x; k < KK; k += 256) {
        float p = (float)counts[k] / (float)NN;
        s += p * logf(p + 1e-10f);
    }
    #pragma unroll
    for (int m = 32; m > 0; m >>= 1) s += __shfl_down(s, m);
    __shared__ float wsum[4];
    if ((threadIdx.x & 63) == 0) wsum[threadIdx.x >> 6] = s;
    __syncthreads();
    if (threadIdx.x == 0) {
        float ent = (wsum[0] + wsum[1]) + (wsum[2] + wsum[3]);
        out[(size_t)BB * DD * TT]     = 1.25f * (*sse) / (float)(BB * DD * TT);
        out[(size_t)BB * DD * TT + 1] = expf(-ent);
    }
}

extern "C" void kernel_launch(void* const* d_in, const int* in_sizes, int n_in,
                              void* d_out, int out_size, void* d_ws, size_t ws_size,
                              hipStream_t stream) {
    const float* z = (const float*)d_in[0];   // (32, 256, 1024) fp32
    const float* W = (const float*)d_in[1];   // (1024, 256) fp32
    float* out = (float*)d_out;               // 8388608 + 2 fp32

    float* wsq    = (float*)d_ws;
    int*   counts = (int*)(wsq + 1024);
    float* sse    = (float*)(counts + 1024);

    prep_kernel<<<1024, 64, 0, stream>>>(W, wsq, counts, sse);
    vq_fused_kernel<<<NN / BROWS, 512, 0, stream>>>(z, W, wsq, out, counts, sse);
    finalize_kernel<<<1, 256, 0, stream>>>(counts, sse, out);
}

// Round 12
// 229.008 us; speedup vs baseline: 4.2602x; 1.1269x over previous
//
#include <hip/hip_runtime.h>
#include <math.h>

// Problem dims (fixed by reference)
#define BB 32
#define DD 256
#define TT 1024
#define KK 1024
#define NN (BB*TT)          // 32768 rows

#define BROWS 128           // rows per block (one block per CU)
#define NSTEP 32            // 2 code-chunks x 16 slices of 16 d

// ws layout (elements): float wsq[1024] @0 ; int counts[1024] @1024 ; float sse @2048

// wsq[k] = sum_d W[k,d]^2 (fp64 accumulate, round once). Zeroes counts+sse.
__global__ void prep_kernel(const float* __restrict__ W, float* __restrict__ wsq,
                            int* __restrict__ counts, float* __restrict__ sse) {
    const int k = blockIdx.x;          // 1024 blocks, 64 threads
    const int lane = threadIdx.x;
    const float4 v = ((const float4*)(W + (size_t)k * DD))[lane];
    double s = (double)v.x * v.x + (double)v.y * v.y + (double)v.z * v.z + (double)v.w * v.w;
    #pragma unroll
    for (int m = 32; m > 0; m >>= 1) s += __shfl_down(s, m);
    if (lane == 0) wsq[k] = (float)s;
    if (blockIdx.x < 16) counts[blockIdx.x * 64 + lane] = 0;
    if (blockIdx.x == 0 && lane == 0) *sse = 0.0f;
}

// async global->LDS, 16B/lane; LDS dest = wave-uniform base + lane*16 (linear).
__device__ __forceinline__ void gl_lds16(const float* g, void* l) {
    __builtin_amdgcn_global_load_lds((const __attribute__((address_space(1))) void*)g,
                                     (__attribute__((address_space(3))) void*)l, 16, 0, 0);
}

// Fused VQ. 512 thr = 8 waves, 1 block/CU (grid 256), 2 waves/SIMD.
// Tile: wave wid owns rows wid*16..+15; lane owns codes {j*64+lane, j=0..7} of
// the current 512-code chunk -> per-thread 16x8 acc.
//  - zst[2][16 d][128 r] (2x8 KB, gl_lds direct; z is t-major so 16B = 4 rows):
//    ALL zf reads are wave-uniform broadcasts.
//  - wst[2] slot-major [j(8)][q(4)][lane(64)] 16B slots (2x32 KB): slot
//    (j,q,l) holds W[chunk + j*64 + l][sl*16 + q*4 .. +3]. For fixed (j,q) the
//    64 lanes read stride-16B (a permutation of slots 0..63) -> CONFLICT-FREE
//    ds_read_b128 (the R11 4-way wf conflict fix); address = one base (q*64+
//    lane) + immediate j*4096B. gl_lds linear dest + inverse-mapped source
//    (scattered 16B reads; W is L2-resident so no HBM cost).
// dist mirrors np: s1 = fl(rowsq+wsq); v = fmaf(-2, dot, s1). Per-(row,code)
// dot: single sequential fmaf chain d=0..255 (t asc -> q asc -> dp asc, one
// fmaf per d) — bitwise same chain as R1-R11 (validated absmax==0.0 9x).
// DO NOT reorder. acc static-indexed only (rule #20); q-loop rolled (R4).
__global__ __launch_bounds__(512, 2) void vq_fused_kernel(
    const float* __restrict__ z, const float* __restrict__ W,
    const float* __restrict__ wsq, float* __restrict__ out,
    int* __restrict__ counts, float* __restrict__ sse)
{
    __shared__ float zst[2][16 * 128];   // 16 KB (zst[0] reused as idx scratch at end)
    __shared__ float wst[2][16 * 512];   // 64 KB (wst[0] reused as sse scratch at end)
    __shared__ float rsql[128];
    const int tid = threadIdx.x;
    const int wid = tid >> 6, lane = tid & 63;
    const int row0 = blockIdx.x * BROWS;
    const int b = row0 >> 10, t0 = row0 & 1023;
    const size_t bbase = (size_t)b * DD * TT;
    const float* zbase = z + bbase + t0;

    // ---- prologue staging for step 0 (ch=0, sl=0); latency hides under rowsq
    {
        char* dw = (char*)&wst[0][0];
        #pragma unroll
        for (int k = 0; k < 4; ++k) {
            const int m = k * 512 + tid;                  // 16B slot index
            const int j = m >> 8, q = (m >> 6) & 3, l = m & 63;
            gl_lds16(W + (size_t)(j * 64 + l) * DD + q * 4, dw + (size_t)m * 16);
        }
        const int d = tid >> 5, r4 = (tid & 31) * 4;
        gl_lds16(zbase + (size_t)d * TT + r4, (char*)&zst[0][0] + (size_t)tid * 16);
    }

    // ---- rowsq: per row 4 fp64 64-d chains, tree (p0+p1)+(p2+p3) (validated form)
    {
        double* pscr = (double*)&zst[1][0];        // 4 KB scratch (zst[1] free pre-loop)
        const int rr = tid & 127, g = tid >> 7;
        const float* zp = zbase + (size_t)g * 64 * TT + rr;
        double s = 0.0;
        #pragma unroll 4
        for (int d = 0; d < 64; ++d) { float v = zp[(size_t)d * TT]; s += (double)v * v; }
        pscr[g * 128 + rr] = s;
        __syncthreads();
        if (tid < 128)
            rsql[tid] = (float)((pscr[tid] + pscr[128 + tid]) + (pscr[256 + tid] + pscr[384 + tid]));
    }

    float minv[16]; int mini[16];
    #pragma unroll
    for (int i = 0; i < 16; ++i) { minv[i] = 3.4e38f; mini[i] = 0; }
    float acc[16][8];

    for (int t = 0; t < NSTEP; ++t) {
        const int ch = t >> 4, sl = t & 15, h = t & 1;
        __syncthreads();   // drains vmcnt/lgkm: buffers[h] (staged at t-1) ready;
                           // at t=0 also fences rowsq scratch in zst[1]
        // issue step t+1 staging NOW; lands during ~4096 cyc of compute below
        if (t + 1 < NSTEP) {
            const int tn = t + 1, chn = tn >> 4, sln = tn & 15;
            const float* wc = W + (size_t)(chn * 512) * DD + sln * 16;
            char* dw = (char*)&wst[tn & 1][0];
            #pragma unroll
            for (int k = 0; k < 4; ++k) {
                const int m = k * 512 + tid;
                const int j = m >> 8, q = (m >> 6) & 3, l = m & 63;
                gl_lds16(wc + (size_t)(j * 64 + l) * DD + q * 4, dw + (size_t)m * 16);
            }
            const int d = tid >> 5, r4 = (tid & 31) * 4;
            gl_lds16(zbase + (size_t)(sln * 16 + d) * TT + r4,
                     (char*)&zst[tn & 1][0] + (size_t)tid * 16);
        }
        if (sl == 0) {
            #pragma unroll
            for (int i = 0; i < 16; ++i)
                #pragma unroll
                for (int j = 0; j < 8; ++j) acc[i][j] = 0.0f;
        }
        // compute: 4 q-groups x (8 wf conflict-free b128 + 4 zf broadcast b128
        // + 512 fmaf/thread)
        const float*  zb  = &zst[h][0];
        const float4* wb4 = (const float4*)&wst[h][0];
        __builtin_amdgcn_s_setprio(1);
        #pragma clang loop unroll(disable)
        for (int q = 0; q < 4; ++q) {
            const float4* wp = wb4 + q * 64 + lane;       // + j*256 (imm j*4096B)
            float4 wf[8];
            #pragma unroll
            for (int j = 0; j < 8; ++j) wf[j] = wp[j * 256];
            #pragma unroll
            for (int dp = 0; dp < 4; ++dp) {
                const float4* zp4 = (const float4*)(zb + (q * 4 + dp) * 128 + wid * 16);
                const float4 za = zp4[0], zc = zp4[1], ze = zp4[2], zg = zp4[3];
                #pragma unroll
                for (int j = 0; j < 8; ++j) {
                    const float wv = dp == 0 ? wf[j].x : dp == 1 ? wf[j].y
                                   : dp == 2 ? wf[j].z : wf[j].w;
                    acc[0][j]  = fmaf(za.x, wv, acc[0][j]);
                    acc[1][j]  = fmaf(za.y, wv, acc[1][j]);
                    acc[2][j]  = fmaf(za.z, wv, acc[2][j]);
                    acc[3][j]  = fmaf(za.w, wv, acc[3][j]);
                    acc[4][j]  = fmaf(zc.x, wv, acc[4][j]);
                    acc[5][j]  = fmaf(zc.y, wv, acc[5][j]);
                    acc[6][j]  = fmaf(zc.z, wv, acc[6][j]);
                    acc[7][j]  = fmaf(zc.w, wv, acc[7][j]);
                    acc[8][j]  = fmaf(ze.x, wv, acc[8][j]);
                    acc[9][j]  = fmaf(ze.y, wv, acc[9][j]);
                    acc[10][j] = fmaf(ze.z, wv, acc[10][j]);
                    acc[11][j] = fmaf(ze.w, wv, acc[11][j]);
                    acc[12][j] = fmaf(zg.x, wv, acc[12][j]);
                    acc[13][j] = fmaf(zg.y, wv, acc[13][j]);
                    acc[14][j] = fmaf(zg.z, wv, acc[14][j]);
                    acc[15][j] = fmaf(zg.w, wv, acc[15][j]);
                }
            }
        }
        __builtin_amdgcn_s_setprio(0);
        if (sl == 15) {
            // score + running argmin (thread codes j*64+lane: j asc = code asc;
            // strict < -> first-min like np.argmin)
            float wq[8];
            #pragma unroll
            for (int j = 0; j < 8; ++j) wq[j] = wsq[ch * 512 + j * 64 + lane];
            #pragma unroll
            for (int i = 0; i < 16; ++i) {
                const float rs = rsql[wid * 16 + i];
                #pragma unroll
                for (int j = 0; j < 8; ++j) {
                    const float s1 = rs + wq[j];             // rounding 1 (np A+B)
                    const float v = fmaf(-2.0f, acc[i][j], s1); // rounding 2 (np (A+B)-2P)
                    if (v < minv[i]) { minv[i] = v; mini[i] = ch * 512 + j * 64 + lane; }
                }
            }
        }
    }

    // ---- per-wave argmin reduce over 64 lanes (explicit index tie-break -> lowest)
    __syncthreads();                     // compute done; zst/wst become scratch
    int* idxs = (int*)&zst[0][0];        // 128 ints
    float* ssescr = (float*)&wst[0][0];  // 8 floats
    #pragma unroll
    for (int i = 0; i < 16; ++i) {
        float v = minv[i]; int ix = mini[i];
        #pragma unroll
        for (int m = 1; m < 64; m <<= 1) {
            float ov = __shfl_xor(v, m);
            int   oi = __shfl_xor(ix, m);
            if (ov < v || (ov == v && oi < ix)) { v = ov; ix = oi; }
        }
        if (lane == 0) {
            idxs[wid * 16 + i] = ix;
            atomicAdd(&counts[ix], 1);
        }
    }
    __syncthreads();

    // ---- fused gather / straight-through / SSE over 128 rows x 256 d
    const int tg = tid & 31;       // 32 t-groups of 4 rows
    const int dg = tid >> 5;       // 16 d-groups of 16
    const int t4 = tg * 4;
    int ixs[4];
    #pragma unroll
    for (int m = 0; m < 4; ++m) ixs[m] = idxs[t4 + m];
    float ssel = 0.0f;
    #pragma unroll
    for (int k4 = 0; k4 < 4; ++k4) {
        const int d0 = dg * 16 + k4 * 4;
        float wr[4][4];
        #pragma unroll
        for (int m = 0; m < 4; ++m) {
            float4 wv = *(const float4*)(W + (size_t)ixs[m] * DD + d0);
            wr[m][0] = wv.x; wr[m][1] = wv.y; wr[m][2] = wv.z; wr[m][3] = wv.w;
        }
        #pragma unroll
        for (int dd = 0; dd < 4; ++dd) {
            const int d = d0 + dd;
            const size_t base = bbase + (size_t)d * TT + t0 + t4;
            float4 zv = *(const float4*)(z + base);
            float e0 = wr[0][dd] - zv.x, e1 = wr[1][dd] - zv.y;
            float e2 = wr[2][dd] - zv.z, e3 = wr[3][dd] - zv.w;
            float4 o;
            o.x = zv.x + e0; o.y = zv.y + e1; o.z = zv.z + e2; o.w = zv.w + e3;
            *(float4*)(out + base) = o;
            ssel += (e0 * e0 + e1 * e1) + (e2 * e2 + e3 * e3);
        }
    }
    #pragma unroll
    for (int m = 32; m > 0; m >>= 1) ssel += __shfl_down(ssel, m);
    if (lane == 0) ssescr[wid] = ssel;
    __syncthreads();
    if (tid == 0)
        atomicAdd(sse, ((ssescr[0] + ssescr[1]) + (ssescr[2] + ssescr[3]))
                     + ((ssescr[4] + ssescr[5]) + (ssescr[6] + ssescr[7])));
}

// reg_loss = 1.25 * sse / numel ; perplexity = exp(-sum p*log(p+1e-10))
__global__ void finalize_kernel(const int* __restrict__ counts, const float* __restrict__ sse,
                                float* __restrict__ out) {
    float s = 0.0f;
    for (int k = threadIdx.x; k < KK; k += 256) {
        float p = (float)counts[k] / (float)NN;
        s += p * logf(p + 1e-10f);
    }
    #pragma unroll
    for (int m = 32; m > 0; m >>= 1) s += __shfl_down(s, m);
    __shared__ float wsum[4];
    if ((threadIdx.x & 63) == 0) wsum[threadIdx.x >> 6] = s;
    __syncthreads();
    if (threadIdx.x == 0) {
        float ent = (wsum[0] + wsum[1]) + (wsum[2] + wsum[3]);
        out[(size_t)BB * DD * TT]     = 1.25f * (*sse) / (float)(BB * DD * TT);
        out[(size_t)BB * DD * TT + 1] = expf(-ent);
    }
}

extern "C" void kernel_launch(void* const* d_in, const int* in_sizes, int n_in,
                              void* d_out, int out_size, void* d_ws, size_t ws_size,
                              hipStream_t stream) {
    const float* z = (const float*)d_in[0];   // (32, 256, 1024) fp32
    const float* W = (const float*)d_in[1];   // (1024, 256) fp32
    float* out = (float*)d_out;               // 8388608 + 2 fp32

    float* wsq    = (float*)d_ws;
    int*   counts = (int*)(wsq + 1024);
    float* sse    = (float*)(counts + 1024);

    prep_kernel<<<1024, 64, 0, stream>>>(W, wsq, counts, sse);
    vq_fused_kernel<<<NN / BROWS, 512, 0, stream>>>(z, W, wsq, out, counts, sse);
    finalize_kernel<<<1, 256, 0, stream>>>(counts, sse, out);
}